// Round 3
// baseline (292.701 us; speedup 1.0000x reference)
//
#include <hip/hip_runtime.h>
#include <hip/hip_bf16.h>

typedef short s16x8 __attribute__((ext_vector_type(8)));
typedef float f32x4 __attribute__((ext_vector_type(4)));

namespace {
constexpr int kB   = 8;
constexpr int kN   = 5000;
constexpr int kE   = 40000;
constexpr int kF   = 64;
constexpr int kFE  = 16;
constexpr int kFil = 96;
constexpr float kEps = 1e-3f;
constexpr int kBN = kB * kN;   // 40000
constexpr int kBE = kB * kE;   // 320000
constexpr int kKp = 160;       // padded K (msg 144->160, upd exact 160)
constexpr int kLd = 168;       // LDS row stride in bf16 elems (bank decorrelation)
constexpr int kBM = 128;       // rows per block
}

// float -> bf16 (RNE) bit-twiddle — kept only for the tiny prep kernel
__device__ inline unsigned short f2bf(float x) {
    unsigned u = __float_as_uint(x);
    u += 0x7FFFu + ((u >> 16) & 1u);
    return (unsigned short)(u >> 16);
}

// 8x fp32 -> 8x bf16 via v_cvt_pk_bf16_f32 (RNE, bitwise-identical to twiddle)
__device__ inline s16x8 pack8(const float4& a, const float4& b) {
    union { s16x8 s; __hip_bfloat162 h[4]; } r;
    r.h[0] = __float22bfloat162_rn(make_float2(a.x, a.y));
    r.h[1] = __float22bfloat162_rn(make_float2(a.z, a.w));
    r.h[2] = __float22bfloat162_rn(make_float2(b.x, b.y));
    r.h[3] = __float22bfloat162_rn(make_float2(b.z, b.w));
    return r.s;
}

// Load 8 consecutive fp32 (16B-aligned) -> bf16x8 A-fragment
__device__ inline s16x8 loadA8(const float* __restrict__ p) {
    const float4* q = reinterpret_cast<const float4*>(p);
    return pack8(q[0], q[1]);
}

// ---------------------------------------------------------------------------
// Prep: W (K,96) fp32 -> WT (96,Kp) bf16, zero-padded K rows. Runs once/call.
// ---------------------------------------------------------------------------
__global__ void prep_wT(const float* __restrict__ Wm, const float* __restrict__ Wu,
                        short* __restrict__ wmT, short* __restrict__ wuT) {
    const int t = blockIdx.x * 256 + threadIdx.x;
    if (t >= 96 * kKp) return;
    const int n = t / kKp, k = t % kKp;
    wmT[t] = (k < 144) ? (short)f2bf(Wm[(size_t)k * 96 + n]) : (short)0;
    wuT[t] = (short)f2bf(Wu[(size_t)k * 96 + n]);
}

// ---------------------------------------------------------------------------
// Shared MFMA GEMM + fp32 bias/ReLU/LN epilogue + store (+fused atomic agg).
// A-frags are per-lane registers (a[ks] = A[row=16w+cl][k=32ks+8quad+j]).
// B-frag: B[k][n=16t+cl] from LDS. C/D: col=lane&15, row=quad*4+reg.
// LN: row lives in one 16-lane quad across 6 N-tiles -> shfl_xor(1,2,4,8).
// Fused agg (msg only): fire-and-forget HW global_atomic_add_f32 per column
// (unsafeAtomicAdd -> no return, no wave stall). Proven in round 1.
// ---------------------------------------------------------------------------
__device__ inline void gemm_ln_store(const s16x8 a[5], const short* sB,
                                     const float* __restrict__ bias,
                                     const float* __restrict__ gamma_,
                                     const float* __restrict__ beta_,
                                     float* __restrict__ out,
                                     const int* __restrict__ edges2,  // msg only
                                     float* __restrict__ aggOut,      // msg only
                                     int rowBase, int rowMax) {
    const int tid  = threadIdx.x;
    const int w    = tid >> 6;
    const int lane = tid & 63;
    const int cl   = lane & 15;
    const int quad = lane >> 4;

    f32x4 acc[6] = {};
#pragma unroll
    for (int ks = 0; ks < 5; ++ks) {
#pragma unroll
        for (int t = 0; t < 6; ++t) {
            s16x8 b = *reinterpret_cast<const s16x8*>(
                sB + (16 * t + cl) * kLd + ks * 32 + quad * 8);
            acc[t] = __builtin_amdgcn_mfma_f32_16x16x32_bf16(a[ks], b, acc[t], 0, 0, 0);
        }
    }

    float bmv[6], gv[6], bv[6];
#pragma unroll
    for (int t = 0; t < 6; ++t) {
        const int c = 16 * t + cl;
        bmv[t] = bias[c]; gv[t] = gamma_[c]; bv[t] = beta_[c];
    }
#pragma unroll
    for (int j = 0; j < 4; ++j) {
        float v0[6];
        float s = 0.f;
#pragma unroll
        for (int t = 0; t < 6; ++t) {
            v0[t] = fmaxf(acc[t][j] + bmv[t], 0.f);
            s += v0[t];
        }
        s += __shfl_xor(s, 1); s += __shfl_xor(s, 2);
        s += __shfl_xor(s, 4); s += __shfl_xor(s, 8);
        const float mu = s * (1.f / 96.f);
        float q = 0.f;
#pragma unroll
        for (int t = 0; t < 6; ++t) {
            const float d = v0[t] - mu;
            q = fmaf(d, d, q);
        }
        q += __shfl_xor(q, 1); q += __shfl_xor(q, 2);
        q += __shfl_xor(q, 4); q += __shfl_xor(q, 8);
        const float inv = rsqrtf(q * (1.f / 96.f) + kEps);
        const int row = rowBase + 16 * w + 4 * quad + j;
        if (row < rowMax) {
            float ov[6];
#pragma unroll
            for (int t = 0; t < 6; ++t)
                ov[t] = (v0[t] - mu) * inv * gv[t] + bv[t];
            float* orow = out + (size_t)row * kFil;
#pragma unroll
            for (int t = 0; t < 6; ++t)
                orow[16 * t + cl] = ov[t];
            if (aggOut) {
                const int ob = row / kE;                    // magic-mul div
                const int dn = edges2[(size_t)row * 2 + 1]; // broadcast, L1-hot
                float* arow = aggOut + ((size_t)ob * kN + dn) * kFil;
#pragma unroll
                for (int t = 0; t < 6; ++t)
                    unsafeAtomicAdd(arow + 16 * t + cl, ov[t]);
            }
        }
    }
}

// ---------------------------------------------------------------------------
// Message layer (MFMA): block = 128 edges, 8 waves, each wave owns 16 rows.
// A-fragments loaded directly from global (nodes/efeat are L2-hot) — no sX.
// Epilogue fuses segment-sum via atomics into agg.
// ---------------------------------------------------------------------------
__global__ __launch_bounds__(512, 4) void msg_mfma(
    const float* __restrict__ nodes, const float* __restrict__ efeat,
    const int* __restrict__ edges, const short* __restrict__ wmT,
    const float* __restrict__ bm, const float* __restrict__ g,
    const float* __restrict__ be, float* __restrict__ out_msg,
    float* __restrict__ agg) {
    __shared__ short sB[96 * kLd];    // 32256 B
    const int tid  = threadIdx.x;
    const int w    = tid >> 6;
    const int lane = tid & 63;
    const int cl   = lane & 15;
    const int quad = lane >> 4;

    const int row = blockIdx.x * kBM + 16 * w + cl;   // 2500*128 = 320000 exact
    const int b   = row / kE;
    const int2 e2 = reinterpret_cast<const int2*>(edges)[row];
    const float* srcp = nodes + ((size_t)b * kN + e2.x) * kF + 8 * quad;
    const float* dstp = nodes + ((size_t)b * kN + e2.y) * kF + 8 * quad;

    s16x8 a[5];
    a[0] = loadA8(srcp);           // k =   0+8q+j
    a[1] = loadA8(srcp + 32);      // k =  32+8q+j
    a[2] = loadA8(dstp);           // k =  64+8q+j
    a[3] = loadA8(dstp + 32);      // k =  96+8q+j
    if (quad < 2) {
        a[4] = loadA8(efeat + (size_t)row * kFE + 8 * quad);  // k = 128..143
    } else {
        s16x8 z = {};
        a[4] = z;                  // zero-pad K 144..159
    }

    for (int i = tid; i < 96 * kKp / 8; i += 512) {   // 1920 16B chunks
        const int n = i / 20, c = i % 20;
        *reinterpret_cast<s16x8*>(sB + n * kLd + 8 * c) =
            *reinterpret_cast<const s16x8*>(wmT + n * kKp + 8 * c);
    }
    __syncthreads();
    gemm_ln_store(a, sB, bm, g, be, out_msg, edges, agg,
                  blockIdx.x * kBM, kBE);
}

// ---------------------------------------------------------------------------
// Update layer (MFMA): block = 128 nodes; X row = [node(64)|agg(96)], K=160.
// ---------------------------------------------------------------------------
__global__ __launch_bounds__(512, 4) void upd_mfma(
    const float* __restrict__ nodes, const float* __restrict__ agg,
    const short* __restrict__ wuT, const float* __restrict__ bu,
    const float* __restrict__ g, const float* __restrict__ be,
    float* __restrict__ out_upd) {
    __shared__ short sB[96 * kLd];
    const int tid  = threadIdx.x;
    const int w    = tid >> 6;
    const int lane = tid & 63;
    const int cl   = lane & 15;
    const int quad = lane >> 4;

    const int node0 = blockIdx.x * kBM + 16 * w + cl;
    const int node  = (node0 < kBN) ? node0 : (kBN - 1);  // clamp loads; store guarded
    const float* np = nodes + (size_t)node * kF + 8 * quad;
    const float* ap = agg + (size_t)node * kFil;

    s16x8 a[5];
    a[0] = loadA8(np);                 // k =   0+8q+j -> node[ 0+8q..]
    a[1] = loadA8(np + 32);            // k =  32+8q+j -> node[32+8q..]
    a[2] = loadA8(ap + 8 * quad);      // k =  64+8q+j -> agg [ 0+8q..]
    a[3] = loadA8(ap + 32 + 8 * quad); // k =  96+8q+j -> agg [32+8q..]
    a[4] = loadA8(ap + 64 + 8 * quad); // k = 128+8q+j -> agg [64+8q..]

    for (int i = tid; i < 96 * kKp / 8; i += 512) {
        const int n = i / 20, c = i % 20;
        *reinterpret_cast<s16x8*>(sB + n * kLd + 8 * c) =
            *reinterpret_cast<const s16x8*>(wuT + n * kKp + 8 * c);
    }
    __syncthreads();
    gemm_ln_store(a, sB, bu, g, be, out_upd, nullptr, nullptr,
                  blockIdx.x * kBM, kBN);
}

extern "C" void kernel_launch(void* const* d_in, const int* in_sizes, int n_in,
                              void* d_out, int out_size, void* d_ws, size_t ws_size,
                              hipStream_t stream) {
    const float* nodes  = (const float*)d_in[0];
    const float* efeat  = (const float*)d_in[1];
    const int*   edges  = (const int*)d_in[2];
    const float* Wm     = (const float*)d_in[3];
    const float* bm     = (const float*)d_in[4];
    const float* ln_m_g = (const float*)d_in[5];
    const float* ln_m_b = (const float*)d_in[6];
    const float* Wu     = (const float*)d_in[7];
    const float* bu     = (const float*)d_in[8];
    const float* ln_u_g = (const float*)d_in[9];
    const float* ln_u_b = (const float*)d_in[10];

    float* out_upd = (float*)d_out;                           // (B,N,96) first
    float* out_msg = (float*)d_out + (size_t)kBN * kFil;      // (B,E,96) second

    // workspace layout; 16B-aligned segments
    short* wmT = (short*)d_ws;                                // 96*160 bf16
    short* wuT = wmT + 96 * kKp;                              // 96*160 bf16
    float* agg = (float*)(wuT + 96 * kKp);                    // B*N*96 floats

    // zero the aggregation buffer (atomic accumulation target)
    hipMemsetAsync(agg, 0, (size_t)kBN * kFil * sizeof(float), stream);
    prep_wT<<<(96 * kKp + 255) / 256, 256, 0, stream>>>(Wm, Wu, wmT, wuT);

    msg_mfma<<<kBE / kBM, 512, 0, stream>>>(
        nodes, efeat, edges, wmT, bm, ln_m_g, ln_m_b, out_msg, agg);
    upd_mfma<<<(kBN + kBM - 1) / kBM, 512, 0, stream>>>(
        nodes, agg, wuT, bu, ln_u_g, ln_u_b, out_upd);
}

// Round 4
// 292.396 us; speedup vs baseline: 1.0010x; 1.0010x over previous
//
#include <hip/hip_runtime.h>
#include <hip/hip_bf16.h>

typedef short s16x8 __attribute__((ext_vector_type(8)));
typedef float f32x4 __attribute__((ext_vector_type(4)));

namespace {
constexpr int kB   = 8;
constexpr int kN   = 5000;
constexpr int kE   = 40000;
constexpr int kF   = 64;
constexpr int kFE  = 16;
constexpr int kFil = 96;
constexpr float kEps = 1e-3f;
constexpr int kBN = kB * kN;   // 40000
constexpr int kBE = kB * kE;   // 320000
constexpr int kKp = 160;       // padded K (msg 144->160, upd exact 160)
constexpr int kLd = 168;       // LDS row stride in bf16 elems (bank decorrelation)
constexpr int kBM = 128;       // rows per block
}

// float -> bf16 (RNE) bit-twiddle — kept only for the tiny prep kernel
__device__ inline unsigned short f2bf(float x) {
    unsigned u = __float_as_uint(x);
    u += 0x7FFFu + ((u >> 16) & 1u);
    return (unsigned short)(u >> 16);
}

// 8x fp32 -> 8x bf16 via v_cvt_pk_bf16_f32 (RNE, bitwise-identical to twiddle)
__device__ inline s16x8 pack8(const float4& a, const float4& b) {
    union { s16x8 s; __hip_bfloat162 h[4]; } r;
    r.h[0] = __float22bfloat162_rn(make_float2(a.x, a.y));
    r.h[1] = __float22bfloat162_rn(make_float2(a.z, a.w));
    r.h[2] = __float22bfloat162_rn(make_float2(b.x, b.y));
    r.h[3] = __float22bfloat162_rn(make_float2(b.z, b.w));
    return r.s;
}

// Load 8 consecutive fp32 (16B-aligned) -> bf16x8 A-fragment
__device__ inline s16x8 loadA8(const float* __restrict__ p) {
    const float4* q = reinterpret_cast<const float4*>(p);
    return pack8(q[0], q[1]);
}

// Packed bf16x2 fire-and-forget atomic add: ONE dword RMW adds two columns.
// ISA-documented family (gfx942-lineage); inline asm so unavailability is a
// clean compile error, not a backend crash. No return value -> no wave stall.
__device__ inline void atomicPkAddBf16(short* addr, float lo, float hi) {
    __hip_bfloat162 v = __float22bfloat162_rn(make_float2(lo, hi));
    unsigned data;
    __builtin_memcpy(&data, &v, 4);
    asm volatile("global_atomic_pk_add_bf16 %0, %1, off"
                 :: "v"((unsigned long long)addr), "v"(data) : "memory");
}

// ---------------------------------------------------------------------------
// Prep: W (K,96) fp32 -> WT (96,Kp) bf16, zero-padded K rows. Runs once/call.
// ---------------------------------------------------------------------------
__global__ void prep_wT(const float* __restrict__ Wm, const float* __restrict__ Wu,
                        short* __restrict__ wmT, short* __restrict__ wuT) {
    const int t = blockIdx.x * 256 + threadIdx.x;
    if (t >= 96 * kKp) return;
    const int n = t / kKp, k = t % kKp;
    wmT[t] = (k < 144) ? (short)f2bf(Wm[(size_t)k * 96 + n]) : (short)0;
    wuT[t] = (short)f2bf(Wu[(size_t)k * 96 + n]);
}

// ---------------------------------------------------------------------------
// Shared MFMA GEMM + fp32 bias/ReLU/LN epilogue + store (+fused atomic agg).
// A-frags are per-lane registers (a[ks] = A[row=16w+cl][k=32ks+8quad+j]).
// B-frag: B[k][n=16t+cl] from LDS. C/D: col=lane&15, row=quad*4+reg.
// LN: row lives in one 16-lane quad across 6 N-tiles -> shfl_xor(1,2,4,8).
// Fused agg (msg only): packed bf16x2 atomics — cols (c,c+1) sit in lane
// pair (cl, cl^1) of the SAME row; one shfl_xor(1) pairs them; even-cl lanes
// issue 6 pk-atomics per row (48 dwords) instead of 96 f32 dwords.
// ---------------------------------------------------------------------------
__device__ inline void gemm_ln_store(const s16x8 a[5], const short* sB,
                                     const float* __restrict__ bias,
                                     const float* __restrict__ gamma_,
                                     const float* __restrict__ beta_,
                                     float* __restrict__ out,
                                     const int* __restrict__ edges2,  // msg only
                                     short* __restrict__ aggOut,      // msg only (bf16)
                                     int rowBase, int rowMax) {
    const int tid  = threadIdx.x;
    const int w    = tid >> 6;
    const int lane = tid & 63;
    const int cl   = lane & 15;
    const int quad = lane >> 4;

    f32x4 acc[6] = {};
#pragma unroll
    for (int ks = 0; ks < 5; ++ks) {
#pragma unroll
        for (int t = 0; t < 6; ++t) {
            s16x8 b = *reinterpret_cast<const s16x8*>(
                sB + (16 * t + cl) * kLd + ks * 32 + quad * 8);
            acc[t] = __builtin_amdgcn_mfma_f32_16x16x32_bf16(a[ks], b, acc[t], 0, 0, 0);
        }
    }

    float bmv[6], gv[6], bv[6];
#pragma unroll
    for (int t = 0; t < 6; ++t) {
        const int c = 16 * t + cl;
        bmv[t] = bias[c]; gv[t] = gamma_[c]; bv[t] = beta_[c];
    }
#pragma unroll
    for (int j = 0; j < 4; ++j) {
        float v0[6];
        float s = 0.f;
#pragma unroll
        for (int t = 0; t < 6; ++t) {
            v0[t] = fmaxf(acc[t][j] + bmv[t], 0.f);
            s += v0[t];
        }
        s += __shfl_xor(s, 1); s += __shfl_xor(s, 2);
        s += __shfl_xor(s, 4); s += __shfl_xor(s, 8);
        const float mu = s * (1.f / 96.f);
        float q = 0.f;
#pragma unroll
        for (int t = 0; t < 6; ++t) {
            const float d = v0[t] - mu;
            q = fmaf(d, d, q);
        }
        q += __shfl_xor(q, 1); q += __shfl_xor(q, 2);
        q += __shfl_xor(q, 4); q += __shfl_xor(q, 8);
        const float inv = rsqrtf(q * (1.f / 96.f) + kEps);
        const int row = rowBase + 16 * w + 4 * quad + j;
        if (row < rowMax) {
            float ov[6];
#pragma unroll
            for (int t = 0; t < 6; ++t)
                ov[t] = (v0[t] - mu) * inv * gv[t] + bv[t];
            float* orow = out + (size_t)row * kFil;
#pragma unroll
            for (int t = 0; t < 6; ++t)
                orow[16 * t + cl] = ov[t];
            if (aggOut) {
                const int ob = row / kE;                    // magic-mul div
                const int dn = edges2[(size_t)row * 2 + 1]; // broadcast, L1-hot
                short* arow = aggOut + ((size_t)ob * kN + dn) * kFil;
#pragma unroll
                for (int t = 0; t < 6; ++t) {
                    const float other = __shfl_xor(ov[t], 1);  // col c^1, same row
                    if ((cl & 1) == 0)
                        atomicPkAddBf16(arow + 16 * t + cl, ov[t], other);
                }
            }
        }
    }
}

// ---------------------------------------------------------------------------
// Message layer (MFMA): block = 128 edges, 8 waves, each wave owns 16 rows.
// A-fragments loaded directly from global (nodes/efeat are L2-hot) — no sX.
// Epilogue fuses segment-sum via packed bf16 atomics into agg.
// ---------------------------------------------------------------------------
__global__ __launch_bounds__(512, 4) void msg_mfma(
    const float* __restrict__ nodes, const float* __restrict__ efeat,
    const int* __restrict__ edges, const short* __restrict__ wmT,
    const float* __restrict__ bm, const float* __restrict__ g,
    const float* __restrict__ be, float* __restrict__ out_msg,
    short* __restrict__ agg) {
    __shared__ short sB[96 * kLd];    // 32256 B
    const int tid  = threadIdx.x;
    const int w    = tid >> 6;
    const int lane = tid & 63;
    const int cl   = lane & 15;
    const int quad = lane >> 4;

    const int row = blockIdx.x * kBM + 16 * w + cl;   // 2500*128 = 320000 exact
    const int b   = row / kE;
    const int2 e2 = reinterpret_cast<const int2*>(edges)[row];
    const float* srcp = nodes + ((size_t)b * kN + e2.x) * kF + 8 * quad;
    const float* dstp = nodes + ((size_t)b * kN + e2.y) * kF + 8 * quad;

    s16x8 a[5];
    a[0] = loadA8(srcp);           // k =   0+8q+j
    a[1] = loadA8(srcp + 32);      // k =  32+8q+j
    a[2] = loadA8(dstp);           // k =  64+8q+j
    a[3] = loadA8(dstp + 32);      // k =  96+8q+j
    if (quad < 2) {
        a[4] = loadA8(efeat + (size_t)row * kFE + 8 * quad);  // k = 128..143
    } else {
        s16x8 z = {};
        a[4] = z;                  // zero-pad K 144..159
    }

    for (int i = tid; i < 96 * kKp / 8; i += 512) {   // 1920 16B chunks
        const int n = i / 20, c = i % 20;
        *reinterpret_cast<s16x8*>(sB + n * kLd + 8 * c) =
            *reinterpret_cast<const s16x8*>(wmT + n * kKp + 8 * c);
    }
    __syncthreads();
    gemm_ln_store(a, sB, bm, g, be, out_msg, edges, agg,
                  blockIdx.x * kBM, kBE);
}

// ---------------------------------------------------------------------------
// Update layer (MFMA): block = 128 nodes; X row = [node(64)|agg(96)], K=160.
// agg is bf16 -> A-fragments for k>=64 are direct 16B loads (no convert).
// ---------------------------------------------------------------------------
__global__ __launch_bounds__(512, 4) void upd_mfma(
    const float* __restrict__ nodes, const short* __restrict__ agg,
    const short* __restrict__ wuT, const float* __restrict__ bu,
    const float* __restrict__ g, const float* __restrict__ be,
    float* __restrict__ out_upd) {
    __shared__ short sB[96 * kLd];
    const int tid  = threadIdx.x;
    const int w    = tid >> 6;
    const int lane = tid & 63;
    const int cl   = lane & 15;
    const int quad = lane >> 4;

    const int node0 = blockIdx.x * kBM + 16 * w + cl;
    const int node  = (node0 < kBN) ? node0 : (kBN - 1);  // clamp loads; store guarded
    const float* np = nodes + (size_t)node * kF + 8 * quad;
    const short* ap = agg + (size_t)node * kFil;

    s16x8 a[5];
    a[0] = loadA8(np);                 // k =   0+8q+j -> node[ 0+8q..]
    a[1] = loadA8(np + 32);            // k =  32+8q+j -> node[32+8q..]
    a[2] = *reinterpret_cast<const s16x8*>(ap + 8 * quad);       // agg[ 0+8q..]
    a[3] = *reinterpret_cast<const s16x8*>(ap + 32 + 8 * quad);  // agg[32+8q..]
    a[4] = *reinterpret_cast<const s16x8*>(ap + 64 + 8 * quad);  // agg[64+8q..]

    for (int i = tid; i < 96 * kKp / 8; i += 512) {
        const int n = i / 20, c = i % 20;
        *reinterpret_cast<s16x8*>(sB + n * kLd + 8 * c) =
            *reinterpret_cast<const s16x8*>(wuT + n * kKp + 8 * c);
    }
    __syncthreads();
    gemm_ln_store(a, sB, bu, g, be, out_upd, nullptr, nullptr,
                  blockIdx.x * kBM, kBN);
}

extern "C" void kernel_launch(void* const* d_in, const int* in_sizes, int n_in,
                              void* d_out, int out_size, void* d_ws, size_t ws_size,
                              hipStream_t stream) {
    const float* nodes  = (const float*)d_in[0];
    const float* efeat  = (const float*)d_in[1];
    const int*   edges  = (const int*)d_in[2];
    const float* Wm     = (const float*)d_in[3];
    const float* bm     = (const float*)d_in[4];
    const float* ln_m_g = (const float*)d_in[5];
    const float* ln_m_b = (const float*)d_in[6];
    const float* Wu     = (const float*)d_in[7];
    const float* bu     = (const float*)d_in[8];
    const float* ln_u_g = (const float*)d_in[9];
    const float* ln_u_b = (const float*)d_in[10];

    float* out_upd = (float*)d_out;                           // (B,N,96) first
    float* out_msg = (float*)d_out + (size_t)kBN * kFil;      // (B,E,96) second

    // workspace layout; 16B-aligned segments
    short* wmT = (short*)d_ws;                                // 96*160 bf16
    short* wuT = wmT + 96 * kKp;                              // 96*160 bf16
    short* agg = wuT + 96 * kKp;                              // B*N*96 bf16 (7.7 MB)

    // zero the aggregation buffer (atomic accumulation target)
    hipMemsetAsync(agg, 0, (size_t)kBN * kFil * sizeof(short), stream);
    prep_wT<<<(96 * kKp + 255) / 256, 256, 0, stream>>>(Wm, Wu, wmT, wuT);

    msg_mfma<<<kBE / kBM, 512, 0, stream>>>(
        nodes, efeat, edges, wmT, bm, ln_m_g, ln_m_b, out_msg, agg);
    upd_mfma<<<(kBN + kBM - 1) / kBM, 512, 0, stream>>>(
        nodes, agg, wuT, bu, ln_u_g, ln_u_b, out_upd);
}